// Round 1
// baseline (410.011 us; speedup 1.0000x reference)
//
#include <hip/hip_runtime.h>

// Bistable stochastic-resonance RK4 scan.
// x, noise: (64, 64, 4096) fp32  -> out: (64, 64, 4096) fp32
// 4096 independent sequences, serial over T=4096.
// Latency-bound on the per-step dependent VALU chain; restructured so the
// critical path is ~12 dependent ops/step:
//   f(y,i) = y*(1-y^2) + i  (a=b=1)
//   y_next = s + h*k = fmaf(h*y, (1-y^2), s + h*i)   [s+h*i, h*y off-chain]
//   s'     = fmaf(H6*y4, w4, fmaf(H6, k1+2k2+2k3, s + 0.1*n + H6*i))

#define T_STEPS 4096
#define N_SEQ   4096

__device__ __forceinline__ float rk4_step(float s, float i, float n) {
    const float H  = 0.01f;          // dt
    const float H2 = 0.005f;         // dt/2
    const float H6 = 0.01f / 6.0f;   // dt/6
    const float SD = 0.1f;           // sqrt(dt), exact fp32 rounding of sqrt(0.01f)

    // Off-critical-path precomputes (depth 1-2 from s)
    float c1    = fmaf(H2, i, s);              // s + h2*i   (stages 2,3)
    float c3    = fmaf(H,  i, s);              // s + h*i    (stage 4 input)
    float basei = fmaf(H6, i, fmaf(SD, n, s)); // s + sqrt_dt*n + h6*i

    // Stage 1: critical chain s -> u1 -> w1 -> y2   (3 deps)
    float u1 = s * s;
    float p1 = H2 * s;
    float w1 = 1.0f - u1;
    float k1 = fmaf(s, w1, i);                 // parallel branch
    float y2 = fmaf(p1, w1, c1);               // = s + h2*k1

    // Stage 2: y2 -> u2 -> w2 -> y3   (3 deps)
    float u2 = y2 * y2;
    float p2 = H2 * y2;
    float w2 = 1.0f - u2;
    float k2 = fmaf(y2, w2, i);                // parallel branch
    float y3 = fmaf(p2, w2, c1);               // = s + h2*k2

    // Stage 3: y3 -> u3 -> w3 -> y4   (3 deps)
    float u3 = y3 * y3;
    float p3 = H * y3;
    float w3 = 1.0f - u3;
    float k3 = fmaf(y3, w3, i);                // parallel branch
    float y4 = fmaf(p3, w3, c3);               // = s + h*k3

    // k-sum on parallel branch
    float t12   = fmaf(2.0f, k2, k1);
    float tsum  = fmaf(2.0f, k3, t12);
    float base2 = fmaf(H6, tsum, basei);

    // Stage 4 folded into the final update: y4 -> u4 -> w4 -> s'  (3 deps)
    float u4 = y4 * y4;
    float z4 = H6 * y4;
    float w4 = 1.0f - u4;
    // s' = base2 + H6*k4, k4 = y4*w4 + i  (H6*i already inside basei)
    return fmaf(z4, w4, base2);
}

__global__ __launch_bounds__(64) void bistable_sr_kernel(
        const float* __restrict__ x,
        const float* __restrict__ noise,
        float* __restrict__ out) {
    const int seq = blockIdx.x * 64 + threadIdx.x;   // [0, 4096)
    const size_t off = (size_t)seq * T_STEPS;

    const float4* __restrict__ px = (const float4*)(x + off);
    const float4* __restrict__ pn = (const float4*)(noise + off);
    float4* __restrict__ po = (float4*)(out + off);

    float s = 0.0f;

    // 2-deep float4 prefetch pipeline: loads are state-independent, so they
    // overlap the serial RK4 chain (8 steps of lead ~ covers L2/HBM latency).
    float4 xv0 = px[0], nv0 = pn[0];
    float4 xv1 = px[1], nv1 = pn[1];

    const int Q = T_STEPS / 4;  // 1024
    for (int q = 0; q < Q; ++q) {
        float4 xc = xv0, nc = nv0;
        xv0 = xv1; nv0 = nv1;
        if (q + 2 < Q) {
            xv1 = px[q + 2];
            nv1 = pn[q + 2];
        }

        float4 o;
        s = rk4_step(s, xc.x, nc.x); o.x = s;
        s = rk4_step(s, xc.y, nc.y); o.y = s;
        s = rk4_step(s, xc.z, nc.z); o.z = s;
        s = rk4_step(s, xc.w, nc.w); o.w = s;
        po[q] = o;
    }
}

extern "C" void kernel_launch(void* const* d_in, const int* in_sizes, int n_in,
                              void* d_out, int out_size, void* d_ws, size_t ws_size,
                              hipStream_t stream) {
    const float* x     = (const float*)d_in[0];
    const float* noise = (const float*)d_in[1];
    float* out = (float*)d_out;

    dim3 grid(N_SEQ / 64);  // 64 blocks -> ~1 wave per CU, each wave alone on a SIMD
    dim3 block(64);
    bistable_sr_kernel<<<grid, block, 0, stream>>>(x, noise, out);
}

// Round 2
// 199.766 us; speedup vs baseline: 2.0525x; 2.0525x over previous
//
#include <hip/hip_runtime.h>

// Bistable stochastic-resonance RK4 scan.
// x, noise: (64, 64, 4096) fp32  -> out: (64, 64, 4096) fp32
// 4096 independent sequences, serial over T=4096. One lane per sequence.
//
// Latency-bound on the serial per-step dependent VALU chain (~12 dep ops,
// ~48 cyc/step). R1 showed ~850 cyc/iter of memory stall: per-lane streams
// are 16KB-strided across lanes, so every 64B-line first touch is a ~900 cyc
// miss and a 2-deep prefetch (~400 cyc lead) cannot hide it.
// R2: 8-iteration-deep register pipeline (16 outstanding loads, static
// indices via full unroll -> stays in VGPRs, compiler emits counted
// s_waitcnt vmcnt(N)). Lead ~1600 cyc > 900 cyc HBM latency.

#define T_STEPS 4096
#define N_SEQ   4096
#define DEPTH   8

__device__ __forceinline__ float rk4_step(float s, float i, float n) {
    const float H  = 0.01f;          // dt
    const float H2 = 0.005f;         // dt/2
    const float H6 = 0.01f / 6.0f;   // dt/6
    const float SD = 0.1f;           // sqrt(dt)

    // Off-critical-path precomputes (depth 1-2 from s)
    float c1    = fmaf(H2, i, s);              // s + h2*i   (stages 2,3)
    float c3    = fmaf(H,  i, s);              // s + h*i    (stage 4 input)
    float basei = fmaf(H6, i, fmaf(SD, n, s)); // s + sqrt_dt*n + h6*i

    // Stage 1: critical chain s -> u1 -> w1 -> y2   (3 deps)
    float u1 = s * s;
    float p1 = H2 * s;
    float w1 = 1.0f - u1;
    float k1 = fmaf(s, w1, i);                 // parallel branch
    float y2 = fmaf(p1, w1, c1);               // = s + h2*k1

    // Stage 2
    float u2 = y2 * y2;
    float p2 = H2 * y2;
    float w2 = 1.0f - u2;
    float k2 = fmaf(y2, w2, i);
    float y3 = fmaf(p2, w2, c1);               // = s + h2*k2

    // Stage 3
    float u3 = y3 * y3;
    float p3 = H * y3;
    float w3 = 1.0f - u3;
    float k3 = fmaf(y3, w3, i);
    float y4 = fmaf(p3, w3, c3);               // = s + h*k3

    // k-sum on parallel branch
    float t12   = fmaf(2.0f, k2, k1);
    float tsum  = fmaf(2.0f, k3, t12);
    float base2 = fmaf(H6, tsum, basei);

    // Stage 4 folded into final update
    float u4 = y4 * y4;
    float z4 = H6 * y4;
    float w4 = 1.0f - u4;
    return fmaf(z4, w4, base2);                // s' = base2 + H6*(y4*w4), H6*i in basei
}

__global__ __launch_bounds__(64) void bistable_sr_kernel(
        const float* __restrict__ x,
        const float* __restrict__ noise,
        float* __restrict__ out) {
    const int seq = blockIdx.x * 64 + threadIdx.x;   // [0, 4096)
    const size_t off = (size_t)seq * T_STEPS;

    const float4* __restrict__ px = (const float4*)(x + off);
    const float4* __restrict__ pn = (const float4*)(noise + off);
    float4* __restrict__ po = (float4*)(out + off);

    // Deep register pipeline. Indices into bx/bn are all compile-time
    // constants (full unroll) so these live in VGPRs, never scratch.
    float4 bx[DEPTH], bn[DEPTH];
#pragma unroll
    for (int j = 0; j < DEPTH; ++j) {
        bx[j] = px[j];
        bn[j] = pn[j];
    }

    float s = 0.0f;
    const int Q = T_STEPS / 4;  // 1024

    for (int qb = 0; qb < Q; qb += DEPTH) {
#pragma unroll
        for (int j = 0; j < DEPTH; ++j) {
            const int q = qb + j;
            float4 xc = bx[j], nc = bn[j];

            // Refill slot j for iteration q+DEPTH (clamped redundant re-read
            // on the last block -> no branch, loads always issued).
            int nq = q + DEPTH;
            nq = (nq < Q) ? nq : (Q - 1);
            bx[j] = px[nq];
            bn[j] = pn[nq];

            float4 o;
            s = rk4_step(s, xc.x, nc.x); o.x = s;
            s = rk4_step(s, xc.y, nc.y); o.y = s;
            s = rk4_step(s, xc.z, nc.z); o.z = s;
            s = rk4_step(s, xc.w, nc.w); o.w = s;
            po[q] = o;
        }
    }
}

extern "C" void kernel_launch(void* const* d_in, const int* in_sizes, int n_in,
                              void* d_out, int out_size, void* d_ws, size_t ws_size,
                              hipStream_t stream) {
    const float* x     = (const float*)d_in[0];
    const float* noise = (const float*)d_in[1];
    float* out = (float*)d_out;

    dim3 grid(N_SEQ / 64);  // 64 blocks; each wave essentially alone on a CU
    dim3 block(64);
    bistable_sr_kernel<<<grid, block, 0, stream>>>(x, noise, out);
}